// Round 6
// baseline (486.721 us; speedup 1.0000x reference)
//
#include <hip/hip_runtime.h>
#include <hip/hip_bf16.h>

typedef unsigned short u16;
typedef unsigned int u32;
typedef __attribute__((ext_vector_type(8))) __bf16 bf16x8;
typedef __attribute__((ext_vector_type(4))) float f32x4;
typedef __attribute__((ext_vector_type(16))) float f32x16;

constexpr int Bz = 2, Sq = 2048, Dm = 1024, Hn = 16, DK = 64;

__device__ __forceinline__ u16 f2bf(float f) {
    u32 u = __builtin_bit_cast(u32, f);
    return (u16)((u + 0x7FFFu + ((u >> 16) & 1u)) >> 16);   // RNE
}

__device__ __forceinline__ u32 pack_bf16(float a, float b) {
#if __has_builtin(__builtin_amdgcn_cvt_pk_bf16_f32)
    return __builtin_bit_cast(u32, __builtin_amdgcn_cvt_pk_bf16_f32(a, b));
#else
    return (u32)f2bf(a) | ((u32)f2bf(b) << 16);
#endif
}

__device__ __forceinline__ bf16x8 lds_frag(const u16* p) {
    return __builtin_bit_cast(bf16x8, *(const uint4*)p);
}
__device__ __forceinline__ bf16x8 gfrag(const u16* p) {
    return __builtin_bit_cast(bf16x8, *(const uint4*)p);
}
__device__ __forceinline__ int swz(int r) { return (r ^ (r >> 3)) & 7; }

// async global->LDS, 16B per lane; dest = wave-uniform base + lane*16
__device__ __forceinline__ void gll16(const u16* g, u16* l) {
    __builtin_amdgcn_global_load_lds(
        (const __attribute__((address_space(1))) void*)g,
        (__attribute__((address_space(3))) void*)l, 16, 0, 0);
}

// ---------------------------------------------------------------------------
// Kernel 1 (fused prep): z<3: cast q/k/v fp32->bf16. z==3:
//   bx<1024 : transpose+cast the 4 weights (64x64 tiles) -> Wt [N,K] bf16
//   bx==1024: mask -> bias f32 array (0 or -1e10*log2e)
// ---------------------------------------------------------------------------
__global__ __launch_bounds__(256) void mha_prep(
    const float* __restrict__ q, const float* __restrict__ k,
    const float* __restrict__ v,
    const float* __restrict__ w0, const float* __restrict__ w1,
    const float* __restrict__ w2, const float* __restrict__ w3,
    const int* __restrict__ mask,
    u16* __restrict__ qkv_dst, u16* __restrict__ wt_dst,
    float* __restrict__ biasg)
{
    __shared__ float tl[64 * 65];
    const int z = blockIdx.z, tid = threadIdx.x;
    if (z < 3) {
        const float* s = (z == 0) ? q : (z == 1) ? k : v;
        u16* d = qkv_dst + (size_t)z * 4 * 1024 * 1024;
        size_t i = ((size_t)blockIdx.x * 256 + tid) * 8;
        float4 a = *(const float4*)(s + i);
        float4 b = *(const float4*)(s + i + 4);
        *(uint4*)(d + i) = make_uint4(pack_bf16(a.x, a.y), pack_bf16(a.z, a.w),
                                      pack_bf16(b.x, b.y), pack_bf16(b.z, b.w));
        return;
    }
    const int bx = blockIdx.x;
    if (bx > 1024) return;
    if (bx == 1024) {   // bias build: 4096 ints
#pragma unroll
        for (int u = 0; u < 4; u++) {
            int4 mm = ((const int4*)mask)[tid * 4 + u];
            float4 bb;
            bb.x = mm.x ? -1.44269504e10f : 0.f;
            bb.y = mm.y ? -1.44269504e10f : 0.f;
            bb.z = mm.z ? -1.44269504e10f : 0.f;
            bb.w = mm.w ? -1.44269504e10f : 0.f;
            ((float4*)biasg)[tid * 4 + u] = bb;
        }
        return;
    }
    // weight transpose: matrix zi, 64x64 tile (tr,tc)
    const int zi = bx >> 8, t = bx & 255, tr = t >> 4, tc = t & 15;
    const float* src = (zi == 0) ? w0 : (zi == 1) ? w1 : (zi == 2) ? w2 : w3;
    u16* d = wt_dst + (size_t)zi * Dm * Dm;
    {
        int r = tid >> 2, cq = (tid & 3) * 16;
        const float* sp = src + (size_t)(tr * 64 + r) * Dm + tc * 64 + cq;
#pragma unroll
        for (int j = 0; j < 4; j++) {
            float4 vv = *(const float4*)(sp + j * 4);
            tl[r * 65 + cq + j * 4 + 0] = vv.x;
            tl[r * 65 + cq + j * 4 + 1] = vv.y;
            tl[r * 65 + cq + j * 4 + 2] = vv.z;
            tl[r * 65 + cq + j * 4 + 3] = vv.w;
        }
    }
    __syncthreads();
    {
        int rr = tid >> 2, cc = (tid & 3) * 16;
        u16* dp = d + (size_t)(tc * 64 + rr) * Dm + tr * 64 + cc;
        u32 px[8];
#pragma unroll
        for (int j = 0; j < 8; j++)
            px[j] = pack_bf16(tl[(cc + 2 * j) * 65 + rr], tl[(cc + 2 * j + 1) * 65 + rr]);
        *(uint4*)dp       = make_uint4(px[0], px[1], px[2], px[3]);
        *(uint4*)(dp + 8) = make_uint4(px[4], px[5], px[6], px[7]);
    }
}

// ---------------------------------------------------------------------------
// GEMM core: C[128 x NI*32] = A[128xK] @ B[NI*32 x K]^T, K=1024, BK=64,
// global_load_lds staging, XOR-swizzled [rows][64] LDS tiles.
// ---------------------------------------------------------------------------
template<int NI>
__device__ __forceinline__ void gemm_core_dma64(
    const u16* __restrict__ Ab, const u16* __restrict__ Bb,
    u16* As, u16* Bs, f32x4 (&acc)[4][NI])
{
    const int tid = threadIdx.x, lane = tid & 63;
    const int wm = (tid >> 7) & 1, wn = (tid >> 6) & 1;
    const int frow = lane & 15, quad = lane >> 4;

#pragma unroll
    for (int mi = 0; mi < 4; mi++)
#pragma unroll
        for (int ni = 0; ni < NI; ni++) acc[mi][ni] = (f32x4){0.f, 0.f, 0.f, 0.f};

    for (int k0 = 0; k0 < 1024; k0 += 64) {
#pragma unroll
        for (int i = 0; i < 4; i++) {
            int id = tid + i * 256, r = id >> 3, c = id & 7;
            gll16(Ab + (size_t)r * 1024 + k0 + (c ^ swz(r)) * 8, As + (size_t)id * 8);
        }
#pragma unroll
        for (int i = 0; i < NI; i++) {
            int id = tid + i * 256, r = id >> 3, c = id & 7;
            gll16(Bb + (size_t)r * 1024 + k0 + (c ^ swz(r)) * 8, Bs + (size_t)id * 8);
        }
        __syncthreads();
#pragma unroll
        for (int ks = 0; ks < 2; ks++) {
            bf16x8 af[4], bfr[NI];
#pragma unroll
            for (int mi = 0; mi < 4; mi++) {
                int r = wm * 64 + mi * 16 + frow;
                af[mi] = lds_frag(As + r * 64 + ((ks * 4 + quad) ^ swz(r)) * 8);
            }
#pragma unroll
            for (int ni = 0; ni < NI; ni++) {
                int r = wn * (NI * 16) + ni * 16 + frow;
                bfr[ni] = lds_frag(Bs + r * 64 + ((ks * 4 + quad) ^ swz(r)) * 8);
            }
#pragma unroll
            for (int mi = 0; mi < 4; mi++)
#pragma unroll
                for (int ni = 0; ni < NI; ni++)
                    acc[mi][ni] = __builtin_amdgcn_mfma_f32_16x16x32_bf16(
                        af[mi], bfr[ni], acc[mi][ni], 0, 0, 0);
        }
        __syncthreads();
    }
}

// ---------------------------------------------------------------------------
// Kernel 2: QKV projections. z=0: Q->[B,H,S,DK]; z=1: K->[B,H,S,DK];
// z=2: swapped operands -> V'^T [B,H,DK,S], coalesced write, with keys
// PERMUTED by swap(bit2,bit3) of s so PV B-operand is register-natural.
// ---------------------------------------------------------------------------
__global__ __launch_bounds__(256) void mha_proj_qkv(
    const u16* __restrict__ Qb, const u16* __restrict__ Kb, const u16* __restrict__ Vb,
    const u16* __restrict__ Wqt, const u16* __restrict__ Wkt, const u16* __restrict__ Wvt,
    const float* __restrict__ bq, const float* __restrict__ bk, const float* __restrict__ bv,
    u16* __restrict__ Qh, u16* __restrict__ Kh, u16* __restrict__ Vt)
{
    __shared__ __align__(16) u16 As[128 * 64];
    __shared__ __align__(16) u16 Bs[128 * 64];
    const int z = blockIdx.z, bx = blockIdx.x;
    const u16* Ab; const u16* Bb; const float* bias;
    int m0, n0;
    if (z < 2) {
        m0 = (bx >> 3) * 128; n0 = (bx & 7) * 128;
        Ab = ((z == 0) ? Qb : Kb) + (size_t)m0 * Dm;
        Bb = ((z == 0) ? Wqt : Wkt) + (size_t)n0 * Dm;
        bias = (z == 0) ? bq : bk;
    } else {
        m0 = (bx & 7) * 128; n0 = (bx >> 3) * 128;
        Ab = Wvt + (size_t)m0 * Dm;
        Bb = Vb + (size_t)n0 * Dm;
        bias = bv;
    }

    f32x4 acc[4][4];
    gemm_core_dma64<4>(Ab, Bb, As, Bs, acc);

    const int tid = threadIdx.x, lane = tid & 63;
    const int wm = (tid >> 7) & 1, wn = (tid >> 6) & 1;
    const int frow = lane & 15, quad = lane >> 4;
    u16* dstq = (z == 0) ? Qh : Kh;
#pragma unroll
    for (int mi = 0; mi < 4; mi++)
#pragma unroll
        for (int ni = 0; ni < 4; ni++)
#pragma unroll
            for (int r = 0; r < 4; r++) {
                int i = m0 + wm * 64 + mi * 16 + quad * 4 + r;
                int j = n0 + wn * 64 + ni * 16 + frow;
                if (z < 2) {
                    float val = acc[mi][ni][r] + bias[j];
                    int b = i >> 11, s = i & (Sq - 1);
                    int h = j >> 6, dk = j & (DK - 1);
                    dstq[((size_t)(b * Hn + h) * Sq + s) * DK + dk] = f2bf(val);
                } else {
                    float val = acc[mi][ni][r] + bias[i];
                    int h = i >> 6, dk = i & (DK - 1);
                    int b = j >> 11, s = j & (Sq - 1);
                    int sp = (s & ~12) | ((s & 4) << 1) | ((s & 8) >> 1);  // swap bits 2,3
                    Vt[((size_t)(b * Hn + h) * DK + dk) * Sq + sp] = f2bf(val);
                }
            }
}

// ---------------------------------------------------------------------------
// Kernel 3: flash attention. 512 thr = 8 waves = 2 q-groups (32q) x 4
// key-parities (32 keys each of a 128-key staged tile). No-max exp2 softmax
// (linear partials); P register-resident (V key-permutation); K/V staged
// via global_load_lds, XOR-swizzled; grid.x = bh so all q-tiles of one head
// share an XCD's L2. Parity partials combined in LDS at epilogue.
// ---------------------------------------------------------------------------
__global__ __launch_bounds__(512, 6) void mha_attn(
    const u16* __restrict__ Qh, const u16* __restrict__ Kh, const u16* __restrict__ Vt,
    const float* __restrict__ biasg, u16* __restrict__ X)
{
    const int bh = blockIdx.x;                 // b*16+h -> XCD = bh%8
    const int b = bh >> 4;
    const int q0 = blockIdx.y * 64;
    const int tid = threadIdx.x, lane = tid & 63, w = tid >> 6;
    const int wq = w & 1, p = w >> 1;          // q-group, key-parity 0..3
    const int qc = lane & 31, half = lane >> 5;
    constexpr float C2 = 0.125f * 1.44269504f; // 1/sqrt(DK) * log2(e)

    __shared__ __align__(16) u16 Ks[128 * 64]; // 16 KB [key][dk]
    __shared__ __align__(16) u16 Vs[64 * 128]; // 16 KB [d][key-slot]
    __shared__ float lsl[128];

    const u16* Qp = Qh + (size_t)bh * Sq * DK;
    const u16* Kp = Kh + (size_t)bh * Sq * DK;
    const u16* Vp = Vt + (size_t)bh * DK * Sq;
    const float* bp = biasg + b * Sq;

    // Q B-frags direct from global (once): lane n=qc; k = kc*16 + half*8 + j
    bf16x8 qf[4];
    {
        const u16* qrow = Qp + (size_t)(q0 + wq * 32 + qc) * DK + half * 8;
#pragma unroll
        for (int kc = 0; kc < 4; kc++) qf[kc] = gfrag(qrow + kc * 16);
    }

    float l_l = 0.f;
    f32x16 o0, o1;
#pragma unroll
    for (int i = 0; i < 16; i++) { o0[i] = 0.f; o1[i] = 0.f; }

    for (int it = 0; it < 16; it++) {
        const int kb = it * 128;
        // ---- stage K [128][64] + V [64][128] (32 KB, 4 gll16/thread) ----
#pragma unroll
        for (int i = 0; i < 2; i++) {
            int id = tid + i * 512;
            int kr = id >> 3, kc_ = id & 7;
            gll16(Kp + (size_t)(kb + kr) * DK + (kc_ ^ swz(kr)) * 8, Ks + (size_t)id * 8);
            int vr = id >> 4, vc = id & 15;
            gll16(Vp + (size_t)vr * Sq + kb + ((vc ^ (vr & 15)) * 8), Vs + (size_t)id * 8);
        }
        __syncthreads();

        // ---- S^T = K Q^T on this wave's 32-key slice ----
        const int kr = p * 32 + qc;
        const int K0 = kb + p * 32;
        f32x16 sT;
#pragma unroll
        for (int i = 0; i < 16; i++) sT[i] = 0.f;
#pragma unroll
        for (int kc = 0; kc < 4; kc++) {
            bf16x8 ka = lds_frag(Ks + kr * 64 + ((kc * 2 + half) ^ swz(kr)) * 8);
            sT = __builtin_amdgcn_mfma_f32_32x32x16_bf16(ka, qf[kc], sT, 0, 0, 0);
        }

        // ---- no-max exp2 softmax; C row(key) = (r&3)+8*(r>>2)+4*half ----
        float t[16], rs = 0.f;
#pragma unroll
        for (int g = 0; g < 4; g++) {
            float4 mb = *(const float4*)(bp + K0 + 8 * g + 4 * half);
#pragma unroll
            for (int r = 0; r < 4; r++) {
                float bb = (r == 0) ? mb.x : (r == 1) ? mb.y : (r == 2) ? mb.z : mb.w;
                float a = __builtin_amdgcn_exp2f(fmaf(sT[g * 4 + r], C2, bb));
                t[g * 4 + r] = a; rs += a;
            }
        }
        l_l += rs;

        // ---- pack P (register-resident; slot = key w/ bits2,3 swapped) ----
        u32 pk[8];
#pragma unroll
        for (int i = 0; i < 8; i++) pk[i] = pack_bf16(t[2 * i], t[2 * i + 1]);

        // ---- O^T += V P^T (2 MFMAs of k=16 per d-half) ----
#pragma unroll
        for (int kc = 0; kc < 2; kc++) {
            bf16x8 pf = __builtin_bit_cast(bf16x8,
                make_uint4(pk[4 * kc], pk[4 * kc + 1], pk[4 * kc + 2], pk[4 * kc + 3]));
            int ch = p * 4 + kc * 2 + half;
            bf16x8 va0 = lds_frag(Vs + qc * 128 + ((ch ^ (qc & 15)) * 8));
            bf16x8 va1 = lds_frag(Vs + (32 + qc) * 128 + ((ch ^ ((32 + qc) & 15)) * 8));
            o0 = __builtin_amdgcn_mfma_f32_32x32x16_bf16(va0, pf, o0, 0, 0, 0);
            o1 = __builtin_amdgcn_mfma_f32_32x32x16_bf16(va1, pf, o1, 0, 0, 0);
        }
        __syncthreads();
    }

    // ---- combine 4 key-parity partials (linear: no max shift) ----
    l_l += __shfl_xor(l_l, 32);
    float* fc = (float*)Ks + wq * 2048;      // 8 KB per q-group
#pragma unroll 1
    for (int src = 1; src < 4; src++) {
        if (p == src) {
#pragma unroll
            for (int r = 0; r < 16; r++) fc[r * 64 + lane] = o0[r];
#pragma unroll
            for (int r = 0; r < 16; r++) fc[(16 + r) * 64 + lane] = o1[r];
            lsl[wq * 64 + lane] = l_l;
        }
        __syncthreads();
        if (p == 0) {
#pragma unroll
            for (int r = 0; r < 16; r++) o0[r] += fc[r * 64 + lane];
#pragma unroll
            for (int r = 0; r < 16; r++) o1[r] += fc[(16 + r) * 64 + lane];
            l_l += lsl[wq * 64 + lane];
        }
        __syncthreads();
    }
    if (p == 0) {
        float inv = 1.0f / l_l;
        const int qg = q0 + wq * 32 + qc;
        u16* Xp = X + (size_t)(b * Sq + qg) * Dm + (bh & 15) * DK;
#pragma unroll
        for (int g = 0; g < 4; g++) {
            *(uint2*)&Xp[8 * g + 4 * half] =
                make_uint2(pack_bf16(o0[g * 4 + 0] * inv, o0[g * 4 + 1] * inv),
                           pack_bf16(o0[g * 4 + 2] * inv, o0[g * 4 + 3] * inv));
            *(uint2*)&Xp[32 + 8 * g + 4 * half] =
                make_uint2(pack_bf16(o1[g * 4 + 0] * inv, o1[g * 4 + 1] * inv),
                           pack_bf16(o1[g * 4 + 2] * inv, o1[g * 4 + 3] * inv));
        }
    }
}

// ---------------------------------------------------------------------------
// Kernel 4: out = X @ Wo + bo (fp32). 128x64 tiles -> 512 blocks.
// ---------------------------------------------------------------------------
__global__ __launch_bounds__(256) void mha_oproj(
    const u16* __restrict__ X, const u16* __restrict__ Wot,
    const float* __restrict__ bo, float* __restrict__ out)
{
    __shared__ __align__(16) u16 As[128 * 64];
    __shared__ __align__(16) u16 Bs[64 * 64];
    const int m0 = blockIdx.y * 128, n0 = blockIdx.x * 64;
    f32x4 acc[4][2];
    gemm_core_dma64<2>(X + (size_t)m0 * Dm, Wot + (size_t)n0 * Dm, As, Bs, acc);
    const int tid = threadIdx.x, lane = tid & 63;
    const int wm = (tid >> 7) & 1, wn = (tid >> 6) & 1;
    const int frow = lane & 15, quad = lane >> 4;
#pragma unroll
    for (int mi = 0; mi < 4; mi++)
#pragma unroll
        for (int ni = 0; ni < 2; ni++)
#pragma unroll
            for (int r = 0; r < 4; r++) {
                int m = m0 + wm * 64 + mi * 16 + quad * 4 + r;
                int n = n0 + wn * 32 + ni * 16 + frow;
                out[(size_t)m * Dm + n] = acc[mi][ni][r] + bo[n];
            }
}

// ---------------------------------------------------------------------------
extern "C" void kernel_launch(void* const* d_in, const int* in_sizes, int n_in,
                              void* d_out, int out_size, void* d_ws, size_t ws_size,
                              hipStream_t stream)
{
    const float* qin  = (const float*)d_in[0];
    const float* kin  = (const float*)d_in[1];
    const float* vin  = (const float*)d_in[2];
    const int*   mask = (const int*)d_in[3];
    const float* Wq   = (const float*)d_in[4];
    const float* bq   = (const float*)d_in[5];
    const float* Wk   = (const float*)d_in[6];
    const float* bk   = (const float*)d_in[7];
    const float* Wv   = (const float*)d_in[8];
    const float* bv   = (const float*)d_in[9];
    const float* Wo   = (const float*)d_in[10];
    const float* bo   = (const float*)d_in[11];
    float* out = (float*)d_out;

    u16* ws = (u16*)d_ws;
    const size_t MW = (size_t)Dm * Dm;
    const size_t MT = (size_t)Bz * Sq * Dm;
    u16* Wqt = ws;
    u16* Wkt = ws + MW;
    u16* Wvt = ws + 2 * MW;
    u16* Wot = ws + 3 * MW;
    u16* Qb  = ws + 4 * MW;
    u16* Kb  = Qb + MT;
    u16* Vb  = Kb + MT;
    u16* Qh  = Vb + MT;
    u16* Kh  = Qh + MT;
    u16* Vt  = Kh + MT;
    float* biasg = (float*)(Vt + MT);   // 16 KB
    u16* X   = Qb;                      // Qb dead after proj

    hipLaunchKernelGGL(mha_prep, dim3(2048, 1, 4), dim3(256), 0, stream,
                       qin, kin, vin, Wq, Wk, Wv, Wo, mask, Qb, Wqt, biasg);
    hipLaunchKernelGGL(mha_proj_qkv, dim3(256, 1, 3), dim3(256), 0, stream,
                       Qb, Kb, Vb, Wqt, Wkt, Wvt, bq, bk, bv, Qh, Kh, Vt);
    hipLaunchKernelGGL(mha_attn, dim3(32, 32), dim3(512), 0, stream,
                       Qh, Kh, Vt, biasg, X);
    hipLaunchKernelGGL(mha_oproj, dim3(16, 32), dim3(256), 0, stream,
                       X, Wot, bo, out);
}

// Round 7
// 255.467 us; speedup vs baseline: 1.9052x; 1.9052x over previous
//
#include <hip/hip_runtime.h>
#include <hip/hip_bf16.h>

typedef unsigned short u16;
typedef unsigned int u32;
typedef __attribute__((ext_vector_type(8))) __bf16 bf16x8;
typedef __attribute__((ext_vector_type(4))) float f32x4;
typedef __attribute__((ext_vector_type(16))) float f32x16;

constexpr int Bz = 2, Sq = 2048, Dm = 1024, Hn = 16, DK = 64;

__device__ __forceinline__ u16 f2bf(float f) {
    u32 u = __builtin_bit_cast(u32, f);
    return (u16)((u + 0x7FFFu + ((u >> 16) & 1u)) >> 16);   // RNE
}

__device__ __forceinline__ u32 pack_bf16(float a, float b) {
#if __has_builtin(__builtin_amdgcn_cvt_pk_bf16_f32)
    return __builtin_bit_cast(u32, __builtin_amdgcn_cvt_pk_bf16_f32(a, b));
#else
    return (u32)f2bf(a) | ((u32)f2bf(b) << 16);
#endif
}

__device__ __forceinline__ bf16x8 lds_frag(const u16* p) {
    return __builtin_bit_cast(bf16x8, *(const uint4*)p);
}
__device__ __forceinline__ bf16x8 gfrag(const u16* p) {
    return __builtin_bit_cast(bf16x8, *(const uint4*)p);
}
__device__ __forceinline__ int swz(int r) { return (r ^ (r >> 3)) & 7; }

// async global->LDS, 16B per lane; dest = wave-uniform base + lane*16
__device__ __forceinline__ void gll16(const u16* g, u16* l) {
    __builtin_amdgcn_global_load_lds(
        (const __attribute__((address_space(1))) void*)g,
        (__attribute__((address_space(3))) void*)l, 16, 0, 0);
}

// ---------------------------------------------------------------------------
// Kernel 1 (fused prep): z<3: cast q/k/v fp32->bf16. z==3:
//   bx<1024 : transpose+cast the 4 weights (64x64 tiles) -> Wt [N,K] bf16
//   bx==1024: mask -> bias f32 array (0 or -1e10*log2e)
// ---------------------------------------------------------------------------
__global__ __launch_bounds__(256) void mha_prep(
    const float* __restrict__ q, const float* __restrict__ k,
    const float* __restrict__ v,
    const float* __restrict__ w0, const float* __restrict__ w1,
    const float* __restrict__ w2, const float* __restrict__ w3,
    const int* __restrict__ mask,
    u16* __restrict__ qkv_dst, u16* __restrict__ wt_dst,
    float* __restrict__ biasg)
{
    __shared__ float tl[64 * 65];
    const int z = blockIdx.z, tid = threadIdx.x;
    if (z < 3) {
        const float* s = (z == 0) ? q : (z == 1) ? k : v;
        u16* d = qkv_dst + (size_t)z * 4 * 1024 * 1024;
        size_t i = ((size_t)blockIdx.x * 256 + tid) * 8;
        float4 a = *(const float4*)(s + i);
        float4 b = *(const float4*)(s + i + 4);
        *(uint4*)(d + i) = make_uint4(pack_bf16(a.x, a.y), pack_bf16(a.z, a.w),
                                      pack_bf16(b.x, b.y), pack_bf16(b.z, b.w));
        return;
    }
    const int bx = blockIdx.x;
    if (bx > 1024) return;
    if (bx == 1024) {   // bias build: 4096 ints
#pragma unroll
        for (int u = 0; u < 4; u++) {
            int4 mm = ((const int4*)mask)[tid * 4 + u];
            float4 bb;
            bb.x = mm.x ? -1.44269504e10f : 0.f;
            bb.y = mm.y ? -1.44269504e10f : 0.f;
            bb.z = mm.z ? -1.44269504e10f : 0.f;
            bb.w = mm.w ? -1.44269504e10f : 0.f;
            ((float4*)biasg)[tid * 4 + u] = bb;
        }
        return;
    }
    // weight transpose: matrix zi, 64x64 tile (tr,tc)
    const int zi = bx >> 8, t = bx & 255, tr = t >> 4, tc = t & 15;
    const float* src = (zi == 0) ? w0 : (zi == 1) ? w1 : (zi == 2) ? w2 : w3;
    u16* d = wt_dst + (size_t)zi * Dm * Dm;
    {
        int r = tid >> 2, cq = (tid & 3) * 16;
        const float* sp = src + (size_t)(tr * 64 + r) * Dm + tc * 64 + cq;
#pragma unroll
        for (int j = 0; j < 4; j++) {
            float4 vv = *(const float4*)(sp + j * 4);
            tl[r * 65 + cq + j * 4 + 0] = vv.x;
            tl[r * 65 + cq + j * 4 + 1] = vv.y;
            tl[r * 65 + cq + j * 4 + 2] = vv.z;
            tl[r * 65 + cq + j * 4 + 3] = vv.w;
        }
    }
    __syncthreads();
    {
        int rr = tid >> 2, cc = (tid & 3) * 16;
        u16* dp = d + (size_t)(tc * 64 + rr) * Dm + tr * 64 + cc;
        u32 px[8];
#pragma unroll
        for (int j = 0; j < 8; j++)
            px[j] = pack_bf16(tl[(cc + 2 * j) * 65 + rr], tl[(cc + 2 * j + 1) * 65 + rr]);
        *(uint4*)dp       = make_uint4(px[0], px[1], px[2], px[3]);
        *(uint4*)(dp + 8) = make_uint4(px[4], px[5], px[6], px[7]);
    }
}

// ---------------------------------------------------------------------------
// GEMM core: C[128 x NI*32] = A[128xK] @ B[NI*32 x K]^T, K=1024, BK=64,
// global_load_lds staging, XOR-swizzled [rows][64] LDS tiles.
// ---------------------------------------------------------------------------
template<int NI>
__device__ __forceinline__ void gemm_core_dma64(
    const u16* __restrict__ Ab, const u16* __restrict__ Bb,
    u16* As, u16* Bs, f32x4 (&acc)[4][NI])
{
    const int tid = threadIdx.x, lane = tid & 63;
    const int wm = (tid >> 7) & 1, wn = (tid >> 6) & 1;
    const int frow = lane & 15, quad = lane >> 4;

#pragma unroll
    for (int mi = 0; mi < 4; mi++)
#pragma unroll
        for (int ni = 0; ni < NI; ni++) acc[mi][ni] = (f32x4){0.f, 0.f, 0.f, 0.f};

    for (int k0 = 0; k0 < 1024; k0 += 64) {
#pragma unroll
        for (int i = 0; i < 4; i++) {
            int id = tid + i * 256, r = id >> 3, c = id & 7;
            gll16(Ab + (size_t)r * 1024 + k0 + (c ^ swz(r)) * 8, As + (size_t)id * 8);
        }
#pragma unroll
        for (int i = 0; i < NI; i++) {
            int id = tid + i * 256, r = id >> 3, c = id & 7;
            gll16(Bb + (size_t)r * 1024 + k0 + (c ^ swz(r)) * 8, Bs + (size_t)id * 8);
        }
        __syncthreads();
#pragma unroll
        for (int ks = 0; ks < 2; ks++) {
            bf16x8 af[4], bfr[NI];
#pragma unroll
            for (int mi = 0; mi < 4; mi++) {
                int r = wm * 64 + mi * 16 + frow;
                af[mi] = lds_frag(As + r * 64 + ((ks * 4 + quad) ^ swz(r)) * 8);
            }
#pragma unroll
            for (int ni = 0; ni < NI; ni++) {
                int r = wn * (NI * 16) + ni * 16 + frow;
                bfr[ni] = lds_frag(Bs + r * 64 + ((ks * 4 + quad) ^ swz(r)) * 8);
            }
#pragma unroll
            for (int mi = 0; mi < 4; mi++)
#pragma unroll
                for (int ni = 0; ni < NI; ni++)
                    acc[mi][ni] = __builtin_amdgcn_mfma_f32_16x16x32_bf16(
                        af[mi], bfr[ni], acc[mi][ni], 0, 0, 0);
        }
        __syncthreads();
    }
}

// ---------------------------------------------------------------------------
// Kernel 2: QKV projections. z=0: Q->[B,H,S,DK]; z=1: K->[B,H,S,DK];
// z=2: swapped operands -> V'^T [B,H,DK,S], coalesced write, with keys
// PERMUTED by swap(bit2,bit3) of s so PV B-operand is register-natural.
// ---------------------------------------------------------------------------
__global__ __launch_bounds__(256) void mha_proj_qkv(
    const u16* __restrict__ Qb, const u16* __restrict__ Kb, const u16* __restrict__ Vb,
    const u16* __restrict__ Wqt, const u16* __restrict__ Wkt, const u16* __restrict__ Wvt,
    const float* __restrict__ bq, const float* __restrict__ bk, const float* __restrict__ bv,
    u16* __restrict__ Qh, u16* __restrict__ Kh, u16* __restrict__ Vt)
{
    __shared__ __align__(16) u16 As[128 * 64];
    __shared__ __align__(16) u16 Bs[128 * 64];
    const int z = blockIdx.z, bx = blockIdx.x;
    const u16* Ab; const u16* Bb; const float* bias;
    int m0, n0;
    if (z < 2) {
        m0 = (bx >> 3) * 128; n0 = (bx & 7) * 128;
        Ab = ((z == 0) ? Qb : Kb) + (size_t)m0 * Dm;
        Bb = ((z == 0) ? Wqt : Wkt) + (size_t)n0 * Dm;
        bias = (z == 0) ? bq : bk;
    } else {
        m0 = (bx & 7) * 128; n0 = (bx >> 3) * 128;
        Ab = Wvt + (size_t)m0 * Dm;
        Bb = Vb + (size_t)n0 * Dm;
        bias = bv;
    }

    f32x4 acc[4][4];
    gemm_core_dma64<4>(Ab, Bb, As, Bs, acc);

    const int tid = threadIdx.x, lane = tid & 63;
    const int wm = (tid >> 7) & 1, wn = (tid >> 6) & 1;
    const int frow = lane & 15, quad = lane >> 4;
    u16* dstq = (z == 0) ? Qh : Kh;
#pragma unroll
    for (int mi = 0; mi < 4; mi++)
#pragma unroll
        for (int ni = 0; ni < 4; ni++)
#pragma unroll
            for (int r = 0; r < 4; r++) {
                int i = m0 + wm * 64 + mi * 16 + quad * 4 + r;
                int j = n0 + wn * 64 + ni * 16 + frow;
                if (z < 2) {
                    float val = acc[mi][ni][r] + bias[j];
                    int b = i >> 11, s = i & (Sq - 1);
                    int h = j >> 6, dk = j & (DK - 1);
                    dstq[((size_t)(b * Hn + h) * Sq + s) * DK + dk] = f2bf(val);
                } else {
                    float val = acc[mi][ni][r] + bias[i];
                    int h = i >> 6, dk = i & (DK - 1);
                    int b = j >> 11, s = j & (Sq - 1);
                    int sp = (s & ~12) | ((s & 4) << 1) | ((s & 8) >> 1);  // swap bits 2,3
                    Vt[((size_t)(b * Hn + h) * DK + dk) * Sq + sp] = f2bf(val);
                }
            }
}

// ---------------------------------------------------------------------------
// Kernel 3: flash attention. 512 thr = 8 waves = 2 q-groups (32q) x 4
// key-parities (32 keys each of a 128-key staged tile). No-max exp2 softmax
// (linear partials); P register-resident (V key-permutation); K/V staged
// via global_load_lds, XOR-swizzled; grid.x = bh so all q-tiles of one head
// share an XCD's L2. Parity partials combined in LDS at epilogue.
// __launch_bounds__(512,4): cap 128 regs -- (512,6) capped at ~85 and
// spilled the f32x16 accumulators to scratch (R6: 1.15 GB HBM, 3.7x slower).
// ---------------------------------------------------------------------------
__global__ __launch_bounds__(512, 4) void mha_attn(
    const u16* __restrict__ Qh, const u16* __restrict__ Kh, const u16* __restrict__ Vt,
    const float* __restrict__ biasg, u16* __restrict__ X)
{
    const int bh = blockIdx.x;                 // b*16+h -> XCD = bh%8
    const int b = bh >> 4;
    const int q0 = blockIdx.y * 64;
    const int tid = threadIdx.x, lane = tid & 63, w = tid >> 6;
    const int wq = w & 1, p = w >> 1;          // q-group, key-parity 0..3
    const int qc = lane & 31, half = lane >> 5;
    constexpr float C2 = 0.125f * 1.44269504f; // 1/sqrt(DK) * log2(e)

    __shared__ __align__(16) u16 Ks[128 * 64]; // 16 KB [key][dk]
    __shared__ __align__(16) u16 Vs[64 * 128]; // 16 KB [d][key-slot]
    __shared__ float lsl[128];

    const u16* Qp = Qh + (size_t)bh * Sq * DK;
    const u16* Kp = Kh + (size_t)bh * Sq * DK;
    const u16* Vp = Vt + (size_t)bh * DK * Sq;
    const float* bp = biasg + b * Sq;

    // Q B-frags direct from global (once): lane n=qc; k = kc*16 + half*8 + j
    bf16x8 qf[4];
    {
        const u16* qrow = Qp + (size_t)(q0 + wq * 32 + qc) * DK + half * 8;
#pragma unroll
        for (int kc = 0; kc < 4; kc++) qf[kc] = gfrag(qrow + kc * 16);
    }

    float l_l = 0.f;
    f32x16 o0, o1;
#pragma unroll
    for (int i = 0; i < 16; i++) { o0[i] = 0.f; o1[i] = 0.f; }

    for (int it = 0; it < 16; it++) {
        const int kb = it * 128;
        // ---- stage K [128][64] + V [64][128] (32 KB, 4 gll16/thread) ----
#pragma unroll
        for (int i = 0; i < 2; i++) {
            int id = tid + i * 512;
            int kr = id >> 3, kc_ = id & 7;
            gll16(Kp + (size_t)(kb + kr) * DK + (kc_ ^ swz(kr)) * 8, Ks + (size_t)id * 8);
            int vr = id >> 4, vc = id & 15;
            gll16(Vp + (size_t)vr * Sq + kb + ((vc ^ (vr & 15)) * 8), Vs + (size_t)id * 8);
        }
        __syncthreads();

        // ---- S^T = K Q^T on this wave's 32-key slice ----
        const int kr = p * 32 + qc;
        const int K0 = kb + p * 32;
        f32x16 sT;
#pragma unroll
        for (int i = 0; i < 16; i++) sT[i] = 0.f;
#pragma unroll
        for (int kc = 0; kc < 4; kc++) {
            bf16x8 ka = lds_frag(Ks + kr * 64 + ((kc * 2 + half) ^ swz(kr)) * 8);
            sT = __builtin_amdgcn_mfma_f32_32x32x16_bf16(ka, qf[kc], sT, 0, 0, 0);
        }

        // ---- no-max exp2 softmax; C row(key) = (r&3)+8*(r>>2)+4*half ----
        float t[16], rs = 0.f;
#pragma unroll
        for (int g = 0; g < 4; g++) {
            float4 mb = *(const float4*)(bp + K0 + 8 * g + 4 * half);
#pragma unroll
            for (int r = 0; r < 4; r++) {
                float bb = (r == 0) ? mb.x : (r == 1) ? mb.y : (r == 2) ? mb.z : mb.w;
                float a = __builtin_amdgcn_exp2f(fmaf(sT[g * 4 + r], C2, bb));
                t[g * 4 + r] = a; rs += a;
            }
        }
        l_l += rs;

        // ---- pack P (register-resident; slot = key w/ bits2,3 swapped) ----
        u32 pk[8];
#pragma unroll
        for (int i = 0; i < 8; i++) pk[i] = pack_bf16(t[2 * i], t[2 * i + 1]);

        // ---- O^T += V P^T (2 MFMAs of k=16 per d-half) ----
#pragma unroll
        for (int kc = 0; kc < 2; kc++) {
            bf16x8 pf = __builtin_bit_cast(bf16x8,
                make_uint4(pk[4 * kc], pk[4 * kc + 1], pk[4 * kc + 2], pk[4 * kc + 3]));
            int ch = p * 4 + kc * 2 + half;
            bf16x8 va0 = lds_frag(Vs + qc * 128 + ((ch ^ (qc & 15)) * 8));
            bf16x8 va1 = lds_frag(Vs + (32 + qc) * 128 + ((ch ^ ((32 + qc) & 15)) * 8));
            o0 = __builtin_amdgcn_mfma_f32_32x32x16_bf16(va0, pf, o0, 0, 0, 0);
            o1 = __builtin_amdgcn_mfma_f32_32x32x16_bf16(va1, pf, o1, 0, 0, 0);
        }
        __syncthreads();
    }

    // ---- combine 4 key-parity partials (linear: no max shift) ----
    l_l += __shfl_xor(l_l, 32);
    float* fc = (float*)Ks + wq * 2048;      // 8 KB per q-group
#pragma unroll 1
    for (int src = 1; src < 4; src++) {
        if (p == src) {
#pragma unroll
            for (int r = 0; r < 16; r++) fc[r * 64 + lane] = o0[r];
#pragma unroll
            for (int r = 0; r < 16; r++) fc[(16 + r) * 64 + lane] = o1[r];
            lsl[wq * 64 + lane] = l_l;
        }
        __syncthreads();
        if (p == 0) {
#pragma unroll
            for (int r = 0; r < 16; r++) o0[r] += fc[r * 64 + lane];
#pragma unroll
            for (int r = 0; r < 16; r++) o1[r] += fc[(16 + r) * 64 + lane];
            l_l += lsl[wq * 64 + lane];
        }
        __syncthreads();
    }
    if (p == 0) {
        float inv = 1.0f / l_l;
        const int qg = q0 + wq * 32 + qc;
        u16* Xp = X + (size_t)(b * Sq + qg) * Dm + (bh & 15) * DK;
#pragma unroll
        for (int g = 0; g < 4; g++) {
            *(uint2*)&Xp[8 * g + 4 * half] =
                make_uint2(pack_bf16(o0[g * 4 + 0] * inv, o0[g * 4 + 1] * inv),
                           pack_bf16(o0[g * 4 + 2] * inv, o0[g * 4 + 3] * inv));
            *(uint2*)&Xp[32 + 8 * g + 4 * half] =
                make_uint2(pack_bf16(o1[g * 4 + 0] * inv, o1[g * 4 + 1] * inv),
                           pack_bf16(o1[g * 4 + 2] * inv, o1[g * 4 + 3] * inv));
        }
    }
}

// ---------------------------------------------------------------------------
// Kernel 4: out = X @ Wo + bo (fp32). 128x64 tiles -> 512 blocks.
// ---------------------------------------------------------------------------
__global__ __launch_bounds__(256) void mha_oproj(
    const u16* __restrict__ X, const u16* __restrict__ Wot,
    const float* __restrict__ bo, float* __restrict__ out)
{
    __shared__ __align__(16) u16 As[128 * 64];
    __shared__ __align__(16) u16 Bs[64 * 64];
    const int m0 = blockIdx.y * 128, n0 = blockIdx.x * 64;
    f32x4 acc[4][2];
    gemm_core_dma64<2>(X + (size_t)m0 * Dm, Wot + (size_t)n0 * Dm, As, Bs, acc);
    const int tid = threadIdx.x, lane = tid & 63;
    const int wm = (tid >> 7) & 1, wn = (tid >> 6) & 1;
    const int frow = lane & 15, quad = lane >> 4;
#pragma unroll
    for (int mi = 0; mi < 4; mi++)
#pragma unroll
        for (int ni = 0; ni < 2; ni++)
#pragma unroll
            for (int r = 0; r < 4; r++) {
                int m = m0 + wm * 64 + mi * 16 + quad * 4 + r;
                int n = n0 + wn * 32 + ni * 16 + frow;
                out[(size_t)m * Dm + n] = acc[mi][ni][r] + bo[n];
            }
}

// ---------------------------------------------------------------------------
extern "C" void kernel_launch(void* const* d_in, const int* in_sizes, int n_in,
                              void* d_out, int out_size, void* d_ws, size_t ws_size,
                              hipStream_t stream)
{
    const float* qin  = (const float*)d_in[0];
    const float* kin  = (const float*)d_in[1];
    const float* vin  = (const float*)d_in[2];
    const int*   mask = (const int*)d_in[3];
    const float* Wq   = (const float*)d_in[4];
    const float* bq   = (const float*)d_in[5];
    const float* Wk   = (const float*)d_in[6];
    const float* bk   = (const float*)d_in[7];
    const float* Wv   = (const float*)d_in[8];
    const float* bv   = (const float*)d_in[9];
    const float* Wo   = (const float*)d_in[10];
    const float* bo   = (const float*)d_in[11];
    float* out = (float*)d_out;

    u16* ws = (u16*)d_ws;
    const size_t MW = (size_t)Dm * Dm;
    const size_t MT = (size_t)Bz * Sq * Dm;
    u16* Wqt = ws;
    u16* Wkt = ws + MW;
    u16* Wvt = ws + 2 * MW;
    u16* Wot = ws + 3 * MW;
    u16* Qb  = ws + 4 * MW;
    u16* Kb  = Qb + MT;
    u16* Vb  = Kb + MT;
    u16* Qh  = Vb + MT;
    u16* Kh  = Qh + MT;
    u16* Vt  = Kh + MT;
    float* biasg = (float*)(Vt + MT);   // 16 KB
    u16* X   = Qb;                      // Qb dead after proj

    hipLaunchKernelGGL(mha_prep, dim3(2048, 1, 4), dim3(256), 0, stream,
                       qin, kin, vin, Wq, Wk, Wv, Wo, mask, Qb, Wqt, biasg);
    hipLaunchKernelGGL(mha_proj_qkv, dim3(256, 1, 3), dim3(256), 0, stream,
                       Qb, Kb, Vb, Wqt, Wkt, Wvt, bq, bk, bv, Qh, Kh, Vt);
    hipLaunchKernelGGL(mha_attn, dim3(32, 32), dim3(512), 0, stream,
                       Qh, Kh, Vt, biasg, X);
    hipLaunchKernelGGL(mha_oproj, dim3(16, 32), dim3(256), 0, stream,
                       X, Wot, bo, out);
}

// Round 8
// 252.294 us; speedup vs baseline: 1.9292x; 1.0126x over previous
//
#include <hip/hip_runtime.h>
#include <hip/hip_bf16.h>

typedef unsigned short u16;
typedef unsigned int u32;
typedef __attribute__((ext_vector_type(8))) __bf16 bf16x8;
typedef __attribute__((ext_vector_type(4))) float f32x4;
typedef __attribute__((ext_vector_type(16))) float f32x16;

constexpr int Bz = 2, Sq = 2048, Dm = 1024, Hn = 16, DK = 64;

__device__ __forceinline__ u16 f2bf(float f) {
    u32 u = __builtin_bit_cast(u32, f);
    return (u16)((u + 0x7FFFu + ((u >> 16) & 1u)) >> 16);   // RNE
}

__device__ __forceinline__ u32 pack_bf16(float a, float b) {
#if __has_builtin(__builtin_amdgcn_cvt_pk_bf16_f32)
    return __builtin_bit_cast(u32, __builtin_amdgcn_cvt_pk_bf16_f32(a, b));
#else
    return (u32)f2bf(a) | ((u32)f2bf(b) << 16);
#endif
}

__device__ __forceinline__ bf16x8 lds_frag(const u16* p) {
    return __builtin_bit_cast(bf16x8, *(const uint4*)p);
}
__device__ __forceinline__ bf16x8 gfrag(const u16* p) {
    return __builtin_bit_cast(bf16x8, *(const uint4*)p);
}
__device__ __forceinline__ int swz(int r) { return (r ^ (r >> 3)) & 7; }

// async global->LDS, 16B per lane; dest = wave-uniform base + lane*16
__device__ __forceinline__ void gll16(const u16* g, u16* l) {
    __builtin_amdgcn_global_load_lds(
        (const __attribute__((address_space(1))) void*)g,
        (__attribute__((address_space(3))) void*)l, 16, 0, 0);
}

// ---------------------------------------------------------------------------
// Kernel 1 (fused prep): z<3: cast q/k/v fp32->bf16. z==3:
//   bx<1024 : transpose+cast the 4 weights (64x64 tiles) -> Wt [N,K] bf16
//   bx==1024: mask -> bias f32 array (0 or -1e10*log2e)
// ---------------------------------------------------------------------------
__global__ __launch_bounds__(256) void mha_prep(
    const float* __restrict__ q, const float* __restrict__ k,
    const float* __restrict__ v,
    const float* __restrict__ w0, const float* __restrict__ w1,
    const float* __restrict__ w2, const float* __restrict__ w3,
    const int* __restrict__ mask,
    u16* __restrict__ qkv_dst, u16* __restrict__ wt_dst,
    float* __restrict__ biasg)
{
    __shared__ float tl[64 * 65];
    const int z = blockIdx.z, tid = threadIdx.x;
    if (z < 3) {
        const float* s = (z == 0) ? q : (z == 1) ? k : v;
        u16* d = qkv_dst + (size_t)z * 4 * 1024 * 1024;
        size_t i = ((size_t)blockIdx.x * 256 + tid) * 8;
        float4 a = *(const float4*)(s + i);
        float4 b = *(const float4*)(s + i + 4);
        *(uint4*)(d + i) = make_uint4(pack_bf16(a.x, a.y), pack_bf16(a.z, a.w),
                                      pack_bf16(b.x, b.y), pack_bf16(b.z, b.w));
        return;
    }
    const int bx = blockIdx.x;
    if (bx > 1024) return;
    if (bx == 1024) {   // bias build: 4096 ints
#pragma unroll
        for (int u = 0; u < 4; u++) {
            int4 mm = ((const int4*)mask)[tid * 4 + u];
            float4 bb;
            bb.x = mm.x ? -1.44269504e10f : 0.f;
            bb.y = mm.y ? -1.44269504e10f : 0.f;
            bb.z = mm.z ? -1.44269504e10f : 0.f;
            bb.w = mm.w ? -1.44269504e10f : 0.f;
            ((float4*)biasg)[tid * 4 + u] = bb;
        }
        return;
    }
    // weight transpose: matrix zi, 64x64 tile (tr,tc)
    const int zi = bx >> 8, t = bx & 255, tr = t >> 4, tc = t & 15;
    const float* src = (zi == 0) ? w0 : (zi == 1) ? w1 : (zi == 2) ? w2 : w3;
    u16* d = wt_dst + (size_t)zi * Dm * Dm;
    {
        int r = tid >> 2, cq = (tid & 3) * 16;
        const float* sp = src + (size_t)(tr * 64 + r) * Dm + tc * 64 + cq;
#pragma unroll
        for (int j = 0; j < 4; j++) {
            float4 vv = *(const float4*)(sp + j * 4);
            tl[r * 65 + cq + j * 4 + 0] = vv.x;
            tl[r * 65 + cq + j * 4 + 1] = vv.y;
            tl[r * 65 + cq + j * 4 + 2] = vv.z;
            tl[r * 65 + cq + j * 4 + 3] = vv.w;
        }
    }
    __syncthreads();
    {
        int rr = tid >> 2, cc = (tid & 3) * 16;
        u16* dp = d + (size_t)(tc * 64 + rr) * Dm + tr * 64 + cc;
        u32 px[8];
#pragma unroll
        for (int j = 0; j < 8; j++)
            px[j] = pack_bf16(tl[(cc + 2 * j) * 65 + rr], tl[(cc + 2 * j + 1) * 65 + rr]);
        *(uint4*)dp       = make_uint4(px[0], px[1], px[2], px[3]);
        *(uint4*)(dp + 8) = make_uint4(px[4], px[5], px[6], px[7]);
    }
}

// ---------------------------------------------------------------------------
// GEMM core: C[128 x 64] = A[128xK] @ B[64 x K]^T, K=1024, BK=64.
// 256 thr = 4 waves (2m x 2n), wave tile 64x32. LDS 24 KB -> 6 blocks/CU.
// global_load_lds staging, XOR-swizzled [rows][64] LDS tiles.
// ---------------------------------------------------------------------------
__device__ __forceinline__ void gemm_core_12864(
    const u16* __restrict__ Ab, const u16* __restrict__ Bb,
    u16* As, u16* Bs, f32x4 (&acc)[4][2])
{
    const int tid = threadIdx.x, lane = tid & 63;
    const int wm = (tid >> 7) & 1, wn = (tid >> 6) & 1;
    const int frow = lane & 15, quad = lane >> 4;

#pragma unroll
    for (int mi = 0; mi < 4; mi++)
#pragma unroll
        for (int ni = 0; ni < 2; ni++) acc[mi][ni] = (f32x4){0.f, 0.f, 0.f, 0.f};

    for (int k0 = 0; k0 < 1024; k0 += 64) {
#pragma unroll
        for (int i = 0; i < 4; i++) {
            int id = tid + i * 256, r = id >> 3, c = id & 7;
            gll16(Ab + (size_t)r * 1024 + k0 + (c ^ swz(r)) * 8, As + (size_t)id * 8);
        }
#pragma unroll
        for (int i = 0; i < 2; i++) {
            int id = tid + i * 256, r = id >> 3, c = id & 7;
            gll16(Bb + (size_t)r * 1024 + k0 + (c ^ swz(r)) * 8, Bs + (size_t)id * 8);
        }
        __syncthreads();
#pragma unroll
        for (int ks = 0; ks < 2; ks++) {
            bf16x8 af[4], bfr[2];
#pragma unroll
            for (int mi = 0; mi < 4; mi++) {
                int r = wm * 64 + mi * 16 + frow;
                af[mi] = lds_frag(As + r * 64 + ((ks * 4 + quad) ^ swz(r)) * 8);
            }
#pragma unroll
            for (int ni = 0; ni < 2; ni++) {
                int r = wn * 32 + ni * 16 + frow;
                bfr[ni] = lds_frag(Bs + r * 64 + ((ks * 4 + quad) ^ swz(r)) * 8);
            }
#pragma unroll
            for (int mi = 0; mi < 4; mi++)
#pragma unroll
                for (int ni = 0; ni < 2; ni++)
                    acc[mi][ni] = __builtin_amdgcn_mfma_f32_16x16x32_bf16(
                        af[mi], bfr[ni], acc[mi][ni], 0, 0, 0);
        }
        __syncthreads();
    }
}

// ---------------------------------------------------------------------------
// Kernel 2: QKV projections, 128x64 tiles, 512 blocks per z.
// z=0: Q->[B,H,S,DK]; z=1: K->[B,H,S,DK]; z=2: swapped operands -> V'^T
// [B,H,DK,S] (keys bit2/3-swapped so PV B-operand is register-natural).
// Block mapping: long dimension major so linear%8 (~XCD) clusters reuse.
// ---------------------------------------------------------------------------
__global__ __launch_bounds__(256) void mha_proj_qkv(
    const u16* __restrict__ Qb, const u16* __restrict__ Kb, const u16* __restrict__ Vb,
    const u16* __restrict__ Wqt, const u16* __restrict__ Wkt, const u16* __restrict__ Wvt,
    const float* __restrict__ bq, const float* __restrict__ bk, const float* __restrict__ bv,
    u16* __restrict__ Qh, u16* __restrict__ Kh, u16* __restrict__ Vt)
{
    __shared__ __align__(16) u16 As[128 * 64];
    __shared__ __align__(16) u16 Bs[64 * 64];
    const int z = blockIdx.z, bx = blockIdx.x;
    const u16* Ab; const u16* Bb; const float* bias;
    int m0, n0;
    if (z < 2) {
        m0 = (bx & 31) * 128;        // m-major: XCD = bx%8 = m%8, A clustered
        n0 = (bx >> 5) * 64;
        Ab = ((z == 0) ? Qb : Kb) + (size_t)m0 * Dm;
        Bb = ((z == 0) ? Wqt : Wkt) + (size_t)n0 * Dm;
        bias = (z == 0) ? bq : bk;
    } else {
        m0 = (bx >> 6) * 128;        // n-major: XCD = bx%8 = n%8, Vb clustered
        n0 = (bx & 63) * 64;
        Ab = Wvt + (size_t)m0 * Dm;
        Bb = Vb + (size_t)n0 * Dm;
        bias = bv;
    }

    f32x4 acc[4][2];
    gemm_core_12864(Ab, Bb, As, Bs, acc);

    const int tid = threadIdx.x, lane = tid & 63;
    const int wm = (tid >> 7) & 1, wn = (tid >> 6) & 1;
    const int frow = lane & 15, quad = lane >> 4;
    u16* dstq = (z == 0) ? Qh : Kh;
#pragma unroll
    for (int mi = 0; mi < 4; mi++)
#pragma unroll
        for (int ni = 0; ni < 2; ni++)
#pragma unroll
            for (int r = 0; r < 4; r++) {
                int i = m0 + wm * 64 + mi * 16 + quad * 4 + r;
                int j = n0 + wn * 32 + ni * 16 + frow;
                if (z < 2) {
                    float val = acc[mi][ni][r] + bias[j];
                    int b = i >> 11, s = i & (Sq - 1);
                    int h = j >> 6, dk = j & (DK - 1);
                    dstq[((size_t)(b * Hn + h) * Sq + s) * DK + dk] = f2bf(val);
                } else {
                    float val = acc[mi][ni][r] + bias[i];
                    int h = i >> 6, dk = i & (DK - 1);
                    int b = j >> 11, s = j & (Sq - 1);
                    int sp = (s & ~12) | ((s & 4) << 1) | ((s & 8) >> 1);  // swap bits 2,3
                    Vt[((size_t)(b * Hn + h) * DK + dk) * Sq + sp] = f2bf(val);
                }
            }
}

// ---------------------------------------------------------------------------
// Kernel 3: flash attention. 512 thr = 8 waves = 2 q-groups (32q) x 4
// key-parities (64 keys each of a 256-key staged tile, processed as two
// 32-key register passes). No-max exp2 softmax (linear partials); P
// register-resident (V key-permutation); K/V staged via global_load_lds,
// XOR-swizzled; grid.x = bh for XCD L2 locality. 8 staging barriers total
// (vs 16 at 128-key tiles). __launch_bounds__(512,4): cap 128 regs --
// (512,6) capped ~85 and spilled accumulators (R6: 1.15 GB HBM, 3.7x).
// ---------------------------------------------------------------------------
__global__ __launch_bounds__(512, 4) void mha_attn(
    const u16* __restrict__ Qh, const u16* __restrict__ Kh, const u16* __restrict__ Vt,
    const float* __restrict__ biasg, u16* __restrict__ X)
{
    const int bh = blockIdx.x;                 // b*16+h -> XCD = bh%8
    const int b = bh >> 4;
    const int q0 = blockIdx.y * 64;
    const int tid = threadIdx.x, lane = tid & 63, w = tid >> 6;
    const int wq = w & 1, p = w >> 1;          // q-group, key-parity 0..3
    const int qc = lane & 31, half = lane >> 5;
    constexpr float C2 = 0.125f * 1.44269504f; // 1/sqrt(DK) * log2(e)

    __shared__ __align__(16) u16 Ks[256 * 64]; // 32 KB [key][dk]
    __shared__ __align__(16) u16 Vs[64 * 256]; // 32 KB [d][key-slot]
    __shared__ float lsl[128];

    const u16* Qp = Qh + (size_t)bh * Sq * DK;
    const u16* Kp = Kh + (size_t)bh * Sq * DK;
    const u16* Vp = Vt + (size_t)bh * DK * Sq;
    const float* bp = biasg + b * Sq;

    // Q B-frags direct from global (once): lane n=qc; k = kc*16 + half*8 + j
    bf16x8 qf[4];
    {
        const u16* qrow = Qp + (size_t)(q0 + wq * 32 + qc) * DK + half * 8;
#pragma unroll
        for (int kc = 0; kc < 4; kc++) qf[kc] = gfrag(qrow + kc * 16);
    }

    float l_l = 0.f;
    f32x16 o0, o1;
#pragma unroll
    for (int i = 0; i < 16; i++) { o0[i] = 0.f; o1[i] = 0.f; }

    for (int it = 0; it < 8; it++) {
        const int kb = it * 256;
        // ---- stage K [256][64] + V [64][256] (64 KB, 8 gll16/thread) ----
#pragma unroll
        for (int i = 0; i < 4; i++) {
            int id = tid + i * 512;                 // 0..2047
            int kr = id >> 3, kc_ = id & 7;
            gll16(Kp + (size_t)(kb + kr) * DK + (kc_ ^ swz(kr)) * 8, Ks + (size_t)id * 8);
            int vr = id >> 5, vc = id & 31;
            gll16(Vp + (size_t)vr * Sq + kb + ((vc ^ (vr & 31)) * 8), Vs + (size_t)id * 8);
        }
        __syncthreads();

#pragma unroll
        for (int s = 0; s < 2; s++) {
            // ---- S^T = K Q^T on this wave's 32-key sub-slice ----
            const int kr = p * 64 + s * 32 + qc;
            const int K0 = kb + p * 64 + s * 32;
            f32x16 sT;
#pragma unroll
            for (int i = 0; i < 16; i++) sT[i] = 0.f;
#pragma unroll
            for (int kc = 0; kc < 4; kc++) {
                bf16x8 ka = lds_frag(Ks + kr * 64 + ((kc * 2 + half) ^ swz(kr)) * 8);
                sT = __builtin_amdgcn_mfma_f32_32x32x16_bf16(ka, qf[kc], sT, 0, 0, 0);
            }

            // ---- no-max exp2 softmax; C row(key) = (r&3)+8*(r>>2)+4*half ----
            float t[16], rs = 0.f;
#pragma unroll
            for (int g = 0; g < 4; g++) {
                float4 mb = *(const float4*)(bp + K0 + 8 * g + 4 * half);
#pragma unroll
                for (int r = 0; r < 4; r++) {
                    float bb = (r == 0) ? mb.x : (r == 1) ? mb.y : (r == 2) ? mb.z : mb.w;
                    float a = __builtin_amdgcn_exp2f(fmaf(sT[g * 4 + r], C2, bb));
                    t[g * 4 + r] = a; rs += a;
                }
            }
            l_l += rs;

            // ---- pack P (register-resident; slot = key w/ bits2,3 swapped) ----
            u32 pk[8];
#pragma unroll
            for (int i = 0; i < 8; i++) pk[i] = pack_bf16(t[2 * i], t[2 * i + 1]);

            // ---- O^T += V P^T (2 MFMAs of k=16 per d-half) ----
#pragma unroll
            for (int kc = 0; kc < 2; kc++) {
                bf16x8 pf = __builtin_bit_cast(bf16x8,
                    make_uint4(pk[4 * kc], pk[4 * kc + 1], pk[4 * kc + 2], pk[4 * kc + 3]));
                int ch = p * 8 + s * 4 + kc * 2 + half;
                bf16x8 va0 = lds_frag(Vs + qc * 256 + ((ch ^ (qc & 31)) * 8));
                bf16x8 va1 = lds_frag(Vs + (32 + qc) * 256 + ((ch ^ ((32 + qc) & 31)) * 8));
                o0 = __builtin_amdgcn_mfma_f32_32x32x16_bf16(va0, pf, o0, 0, 0, 0);
                o1 = __builtin_amdgcn_mfma_f32_32x32x16_bf16(va1, pf, o1, 0, 0, 0);
            }
        }
        __syncthreads();
    }

    // ---- combine 4 key-parity partials (linear: no max shift) ----
    l_l += __shfl_xor(l_l, 32);
    float* fc = (float*)Ks + wq * 2048;      // 8 KB per q-group
#pragma unroll 1
    for (int src = 1; src < 4; src++) {
        if (p == src) {
#pragma unroll
            for (int r = 0; r < 16; r++) fc[r * 64 + lane] = o0[r];
#pragma unroll
            for (int r = 0; r < 16; r++) fc[(16 + r) * 64 + lane] = o1[r];
            lsl[wq * 64 + lane] = l_l;
        }
        __syncthreads();
        if (p == 0) {
#pragma unroll
            for (int r = 0; r < 16; r++) o0[r] += fc[r * 64 + lane];
#pragma unroll
            for (int r = 0; r < 16; r++) o1[r] += fc[(16 + r) * 64 + lane];
            l_l += lsl[wq * 64 + lane];
        }
        __syncthreads();
    }
    if (p == 0) {
        float inv = 1.0f / l_l;
        const int qg = q0 + wq * 32 + qc;
        u16* Xp = X + (size_t)(b * Sq + qg) * Dm + (bh & 15) * DK;
#pragma unroll
        for (int g = 0; g < 4; g++) {
            *(uint2*)&Xp[8 * g + 4 * half] =
                make_uint2(pack_bf16(o0[g * 4 + 0] * inv, o0[g * 4 + 1] * inv),
                           pack_bf16(o0[g * 4 + 2] * inv, o0[g * 4 + 3] * inv));
            *(uint2*)&Xp[32 + 8 * g + 4 * half] =
                make_uint2(pack_bf16(o1[g * 4 + 0] * inv, o1[g * 4 + 1] * inv),
                           pack_bf16(o1[g * 4 + 2] * inv, o1[g * 4 + 3] * inv));
        }
    }
}

// ---------------------------------------------------------------------------
// Kernel 4: out = X @ Wo + bo (fp32). 128x64 tiles, m-major -> 512 blocks.
// ---------------------------------------------------------------------------
__global__ __launch_bounds__(256) void mha_oproj(
    const u16* __restrict__ X, const u16* __restrict__ Wot,
    const float* __restrict__ bo, float* __restrict__ out)
{
    __shared__ __align__(16) u16 As[128 * 64];
    __shared__ __align__(16) u16 Bs[64 * 64];
    const int bx = blockIdx.x;
    const int m0 = (bx & 31) * 128, n0 = (bx >> 5) * 64;
    f32x4 acc[4][2];
    gemm_core_12864(X + (size_t)m0 * Dm, Wot + (size_t)n0 * Dm, As, Bs, acc);
    const int tid = threadIdx.x, lane = tid & 63;
    const int wm = (tid >> 7) & 1, wn = (tid >> 6) & 1;
    const int frow = lane & 15, quad = lane >> 4;
#pragma unroll
    for (int mi = 0; mi < 4; mi++)
#pragma unroll
        for (int ni = 0; ni < 2; ni++)
#pragma unroll
            for (int r = 0; r < 4; r++) {
                int m = m0 + wm * 64 + mi * 16 + quad * 4 + r;
                int n = n0 + wn * 32 + ni * 16 + frow;
                out[(size_t)m * Dm + n] = acc[mi][ni][r] + bo[n];
            }
}

// ---------------------------------------------------------------------------
extern "C" void kernel_launch(void* const* d_in, const int* in_sizes, int n_in,
                              void* d_out, int out_size, void* d_ws, size_t ws_size,
                              hipStream_t stream)
{
    const float* qin  = (const float*)d_in[0];
    const float* kin  = (const float*)d_in[1];
    const float* vin  = (const float*)d_in[2];
    const int*   mask = (const int*)d_in[3];
    const float* Wq   = (const float*)d_in[4];
    const float* bq   = (const float*)d_in[5];
    const float* Wk   = (const float*)d_in[6];
    const float* bk   = (const float*)d_in[7];
    const float* Wv   = (const float*)d_in[8];
    const float* bv   = (const float*)d_in[9];
    const float* Wo   = (const float*)d_in[10];
    const float* bo   = (const float*)d_in[11];
    float* out = (float*)d_out;

    u16* ws = (u16*)d_ws;
    const size_t MW = (size_t)Dm * Dm;
    const size_t MT = (size_t)Bz * Sq * Dm;
    u16* Wqt = ws;
    u16* Wkt = ws + MW;
    u16* Wvt = ws + 2 * MW;
    u16* Wot = ws + 3 * MW;
    u16* Qb  = ws + 4 * MW;
    u16* Kb  = Qb + MT;
    u16* Vb  = Kb + MT;
    u16* Qh  = Vb + MT;
    u16* Kh  = Qh + MT;
    u16* Vt  = Kh + MT;
    float* biasg = (float*)(Vt + MT);   // 16 KB
    u16* X   = Qb;                      // Qb dead after proj

    hipLaunchKernelGGL(mha_prep, dim3(2048, 1, 4), dim3(256), 0, stream,
                       qin, kin, vin, Wq, Wk, Wv, Wo, mask, Qb, Wqt, biasg);
    hipLaunchKernelGGL(mha_proj_qkv, dim3(512, 1, 3), dim3(256), 0, stream,
                       Qb, Kb, Vb, Wqt, Wkt, Wvt, bq, bk, bv, Qh, Kh, Vt);
    hipLaunchKernelGGL(mha_attn, dim3(32, 32), dim3(512), 0, stream,
                       Qh, Kh, Vt, biasg, X);
    hipLaunchKernelGGL(mha_oproj, dim3(512), dim3(256), 0, stream,
                       X, Wot, bo, out);
}